// Round 6
// baseline (371.262 us; speedup 1.0000x reference)
//
#include <hip/hip_runtime.h>

typedef float  f32x4 __attribute__((ext_vector_type(4)));
typedef short  s16x8 __attribute__((ext_vector_type(8)));
typedef unsigned short u16x8 __attribute__((ext_vector_type(8)));

#define NROWS 4096
#define FOUT  256
#define ALPHA_LR 0.2f
#define SCALE 0.0625f

static __device__ __forceinline__ unsigned short bf16_rne(float x) {
    unsigned u = __float_as_uint(x);
    u += 0x7fffu + ((u >> 16) & 1u);
    return (unsigned short)(u >> 16);
}
static __device__ __forceinline__ unsigned short bf16_trunc(float x) {
    return (unsigned short)(__float_as_uint(x) >> 16);
}
static __device__ __forceinline__ float bf2f(unsigned short h) {
    return __uint_as_float(((unsigned)h) << 16);
}
static __device__ __forceinline__ float wmax16(float v) {
#pragma unroll
    for (int o = 8; o; o >>= 1) v = fmaxf(v, __shfl_xor(v, o, 16));
    return v;
}
static __device__ __forceinline__ float wsum16(float v) {
#pragma unroll
    for (int o = 8; o; o >>= 1) v += __shfl_xor(v, o, 16);
    return v;
}
static __device__ __forceinline__ float wsum32(float v) {
#pragma unroll
    for (int o = 16; o; o >>= 1) v += __shfl_xor(v, o, 32);
    return v;
}

// ---------------------------------------------------------------------------
// Convert W (512x256) and Wqkv_w (768x256) to bf16 hi/lo.
// ---------------------------------------------------------------------------
__global__ __launch_bounds__(256) void wprep(
    const float* __restrict__ W, const float* __restrict__ Wq,
    unsigned short* __restrict__ Whi, unsigned short* __restrict__ Wlo,
    unsigned short* __restrict__ Qhi, unsigned short* __restrict__ Qlo)
{
    int i = blockIdx.x * 256 + threadIdx.x;
    if (i < 131072) {
        float v = W[i];
        unsigned short hh = bf16_trunc(v);
        Whi[i] = hh; Wlo[i] = bf16_rne(v - bf2f(hh));
    }
    if (i < 196608) {
        float v = Wq[i];
        unsigned short hh = bf16_trunc(v);
        Qhi[i] = hh; Qlo[i] = bf16_rne(v - bf2f(hh));
    }
}

// ---------------------------------------------------------------------------
// MFMA GEMM, 3-term bf16 hi/lo split. (unchanged from round 5)
// ---------------------------------------------------------------------------
template <int EPI, bool BIAS>
__global__ __launch_bounds__(256) void gemm_mfma(
    const float* __restrict__ A,
    const unsigned short* __restrict__ Bhi, const unsigned short* __restrict__ Blo,
    const float* __restrict__ bias,
    float* __restrict__ C, unsigned short* __restrict__ o0,
    unsigned short* __restrict__ o1, unsigned short* __restrict__ o2,
    int M, int Nn, int K)
{
    __shared__ unsigned short Ah[64][40];
    __shared__ unsigned short Al[64][40];
    __shared__ unsigned short Bh[64][40];
    __shared__ unsigned short Bl[64][40];

    const int tid = threadIdx.x;
    const int w = tid >> 6;
    const int ln = tid & 63;
    const int l15 = ln & 15;
    const int lhi = ln >> 4;
    const int bm = blockIdx.y * 64;
    const int bn = blockIdx.x * 64;
    const int sm = tid >> 2;
    const int sk = (tid & 3) * 8;

    f32x4 acc[4];
#pragma unroll
    for (int cf = 0; cf < 4; ++cf) acc[cf] = (f32x4){0.f, 0.f, 0.f, 0.f};

    const float* arow = &A[(size_t)(bm + sm) * K];
    const unsigned short* bhrow = &Bhi[(size_t)(bn + sm) * K];
    const unsigned short* blrow = &Blo[(size_t)(bn + sm) * K];

    float4 a0r = *(const float4*)(arow + sk);
    float4 a1r = *(const float4*)(arow + sk + 4);
    uint4 bhr = *(const uint4*)(bhrow + sk);
    uint4 blr = *(const uint4*)(blrow + sk);

    for (int k0 = 0; k0 < K; k0 += 32) {
        float vv[8] = {a0r.x, a0r.y, a0r.z, a0r.w, a1r.x, a1r.y, a1r.z, a1r.w};
        unsigned hp[4], lp[4];
#pragma unroll
        for (int q = 0; q < 4; ++q) {
            unsigned short h0 = bf16_trunc(vv[q * 2]);
            unsigned short h1 = bf16_trunc(vv[q * 2 + 1]);
            unsigned short l0 = bf16_rne(vv[q * 2] - bf2f(h0));
            unsigned short l1 = bf16_rne(vv[q * 2 + 1] - bf2f(h1));
            hp[q] = (unsigned)h0 | ((unsigned)h1 << 16);
            lp[q] = (unsigned)l0 | ((unsigned)l1 << 16);
        }
        __syncthreads();
        *(uint4*)&Ah[sm][sk] = make_uint4(hp[0], hp[1], hp[2], hp[3]);
        *(uint4*)&Al[sm][sk] = make_uint4(lp[0], lp[1], lp[2], lp[3]);
        *(uint4*)&Bh[sm][sk] = bhr;
        *(uint4*)&Bl[sm][sk] = blr;
        const int kn = (k0 + 32 < K) ? k0 + 32 : 0;
        a0r = *(const float4*)(arow + kn + sk);
        a1r = *(const float4*)(arow + kn + sk + 4);
        bhr = *(const uint4*)(bhrow + kn + sk);
        blr = *(const uint4*)(blrow + kn + sk);
        __syncthreads();
        s16x8 ah = *(const s16x8*)&Ah[w * 16 + l15][lhi * 8];
        s16x8 al2 = *(const s16x8*)&Al[w * 16 + l15][lhi * 8];
        __builtin_amdgcn_s_setprio(1);
#pragma unroll
        for (int cf = 0; cf < 4; ++cf) {
            s16x8 bh = *(const s16x8*)&Bh[cf * 16 + l15][lhi * 8];
            s16x8 bl = *(const s16x8*)&Bl[cf * 16 + l15][lhi * 8];
            acc[cf] = __builtin_amdgcn_mfma_f32_16x16x32_bf16(ah, bh, acc[cf], 0, 0, 0);
            acc[cf] = __builtin_amdgcn_mfma_f32_16x16x32_bf16(ah, bl, acc[cf], 0, 0, 0);
            acc[cf] = __builtin_amdgcn_mfma_f32_16x16x32_bf16(al2, bh, acc[cf], 0, 0, 0);
        }
        __builtin_amdgcn_s_setprio(0);
    }

#pragma unroll
    for (int cf = 0; cf < 4; ++cf) {
        const int col = bn + cf * 16 + l15;
        float bv = BIAS ? bias[col] : 0.0f;
#pragma unroll
        for (int r = 0; r < 4; ++r) {
            const int row = bm + w * 16 + lhi * 4 + r;
            float v = acc[cf][r] + bv;
            if (EPI == 1) {
                C[(size_t)row * Nn + col] = v;
                o0[(size_t)col * NROWS + row] = bf16_rne(v);
            } else if (EPI == 2) {
                if (col < 256)      o0[(size_t)row * 256 + col] = bf16_rne(v);
                else if (col < 512) o1[(size_t)row * 256 + (col - 256)] = bf16_rne(v);
                else                o2[(size_t)(col - 512) * NROWS + row] = bf16_rne(v);
            } else {
                unsigned short hh = bf16_trunc(v);
                o0[(size_t)row * Nn + col] = hh;
                o1[(size_t)row * Nn + col] = bf16_rne(v - bf2f(hh));
            }
        }
    }
}

// ---------------------------------------------------------------------------
// p1 = Wh @ a[:256], p2 = Wh @ a[256:]
// ---------------------------------------------------------------------------
__global__ __launch_bounds__(256) void compute_p(
    const float* __restrict__ Wh, const float* __restrict__ a,
    float* __restrict__ p1, float* __restrict__ p2)
{
    const int row = blockIdx.x * 16 + (threadIdx.x >> 4);
    const int c = threadIdx.x & 15;
    float s1 = 0.f, s2 = 0.f;
    for (int f = c; f < FOUT; f += 16) {
        float w = Wh[(size_t)row * FOUT + f];
        s1 += w * a[f];
        s2 += w * a[FOUT + f];
    }
    s1 = wsum16(s1);
    s2 = wsum16(s2);
    if (c == 0) { p1[row] = s1; p2[row] = s2; }
}

// ---------------------------------------------------------------------------
// Global max of p2 (single block).
// ---------------------------------------------------------------------------
__global__ __launch_bounds__(256) void p2max_kernel(
    const float* __restrict__ p2, float* __restrict__ p2m)
{
    __shared__ float red[4];
    const int tid = threadIdx.x;
    float v = -3.0e38f;
#pragma unroll
    for (int k = 0; k < 16; ++k) v = fmaxf(v, p2[tid + k * 256]);
#pragma unroll
    for (int o = 32; o; o >>= 1) v = fmaxf(v, __shfl_xor(v, o, 64));
    if ((tid & 63) == 0) red[tid >> 6] = v;
    __syncthreads();
    if (tid == 0) p2m[0] = fmaxf(fmaxf(red[0], red[1]), fmaxf(red[2], red[3]));
}

// ---------------------------------------------------------------------------
// Inner-attention stats, j-parallel: grid = 4 chunks x 256 rowtiles
// (chunk-major dispatch). Writes per-chunk (m, z).
// ---------------------------------------------------------------------------
__global__ __launch_bounds__(256) void stats_kernel(
    const unsigned short* __restrict__ qh_g, const unsigned short* __restrict__ kh_g,
    float* __restrict__ stats)
{
    const int tid = threadIdx.x;
    const int h = tid >> 6;
    const int ln = tid & 63;
    const int l15 = ln & 15;
    const int lhi = ln >> 4;
    const int rt = blockIdx.x & 255;
    const int ch = blockIdx.x >> 8;
    const int i0 = rt * 16;

    s16x8 qA[2];
#pragma unroll
    for (int ks = 0; ks < 2; ++ks)
        qA[ks] = *(const s16x8*)(qh_g + (size_t)(i0 + l15) * 256 + h * 64 + ks * 32 + lhi * 8);

    float m[4], z[4];
#pragma unroll
    for (int r = 0; r < 4; ++r) { m[r] = -3.0e38f; z[r] = 0.f; }

    for (int tt = 0; tt < 32; ++tt) {
        const int j0 = ch * 1024 + tt * 32;
        f32x4 acc[2] = {{0.f,0.f,0.f,0.f},{0.f,0.f,0.f,0.f}};
#pragma unroll
        for (int ks = 0; ks < 2; ++ks)
#pragma unroll
            for (int nt = 0; nt < 2; ++nt) {
                s16x8 kB = *(const s16x8*)(kh_g + (size_t)(j0 + nt * 16 + l15) * 256 +
                                           h * 64 + ks * 32 + lhi * 8);
                acc[nt] = __builtin_amdgcn_mfma_f32_16x16x32_bf16(qA[ks], kB, acc[nt], 0, 0, 0);
            }
#pragma unroll
        for (int r = 0; r < 4; ++r) {
            float s0 = acc[0][r] * SCALE, s1 = acc[1][r] * SCALE;
            float mn = fmaxf(m[r], fmaxf(s0, s1));
            z[r] = z[r] * __expf(m[r] - mn) + __expf(s0 - mn) + __expf(s1 - mn);
            m[r] = mn;
        }
    }
#pragma unroll
    for (int r = 0; r < 4; ++r) {
        float mm = m[r], zz = z[r];
#pragma unroll
        for (int o = 1; o < 16; o <<= 1) {
            float mo = __shfl_xor(mm, o, 16);
            float zo = __shfl_xor(zz, o, 16);
            float mn = fmaxf(mm, mo);
            zz = zz * __expf(mm - mn) + zo * __expf(mo - mn);
            mm = mn;
        }
        if (l15 == 0) {
            size_t idx = (((size_t)(i0 + lhi * 4 + r) * 4 + h) * 4 + ch) * 2;
            stats[idx] = mm;
            stats[idx + 1] = zz;
        }
    }
}

// ---------------------------------------------------------------------------
// Main fused sweep v3: FIXED outer-softmax reference max (no online rescale,
// no shuffle chains in the loop). grid = 3 chunks x 256 rowtiles (chunk-major,
// 768 blocks = 3/CU exactly). 512 thr = 8 waves = (head h) x (j-half jg).
// Chunk tiles: 43/43/42 of 32 j. 2 barriers/tile, 1-tile register prefetch.
// ---------------------------------------------------------------------------
__global__ __launch_bounds__(512, 6) void main_attn(
    const unsigned short* __restrict__ qh_g, const unsigned short* __restrict__ kh_g,
    const unsigned short* __restrict__ vth_g, const unsigned short* __restrict__ wht_g,
    const float* __restrict__ stats, const float* __restrict__ p1g,
    const float* __restrict__ p2g, const float* __restrict__ p2m,
    const int* __restrict__ adj,
    unsigned short* __restrict__ pacc_o, unsigned short* __restrict__ wacc_o,
    float* __restrict__ ml_o)
{
    enum { DOTS = 0, PTIL = 5120, MIZ = 6400, SMEMSZ = 6912 };
    __shared__ __align__(16) char smem[SMEMSZ];

    const int tid = threadIdx.x;
    const int w = tid >> 6;
    const int h = w & 3;
    const int jg = w >> 2;
    const int ln = tid & 63;
    const int l15 = ln & 15;
    const int lhi = ln >> 4;
    const int rt = blockIdx.x & 255;
    const int ch = blockIdx.x >> 8;
    const int i0 = rt * 16;
    const int jbase = ch * 1376;
    const int ntiles = (ch == 2) ? 42 : 43;
    const int srow = tid >> 5;      // 0..15
    const int scol = tid & 31;      // 0..31

    // ---- merge inner-stats partials (4 chunks) ----
    if (tid < 64) {
        int hh = tid >> 4, row = tid & 15;
        const float* sb = stats + ((size_t)(i0 + row) * 4 + hh) * 8;
        float M = -3.0e38f, Z = 0.f;
#pragma unroll
        for (int c = 0; c < 4; ++c) {
            float mc = sb[c * 2], zc = sb[c * 2 + 1];
            float mn = fmaxf(M, mc);
            Z = Z * __expf(M - mn) + zc * __expf(mc - mn);
            M = mn;
        }
        ((float*)(smem + MIZ))[(hh * 16 + row) * 2] = M;
        ((float*)(smem + MIZ))[(hh * 16 + row) * 2 + 1] = 1.0f / Z;
    }

    // persistent q fragments
    s16x8 qA[2];
#pragma unroll
    for (int ks = 0; ks < 2; ++ks)
        qA[ks] = *(const s16x8*)(qh_g + (size_t)(i0 + l15) * 256 + h * 64 + ks * 32 + lhi * 8);

    __syncthreads();

    float m_f[4], iz_f[4];
#pragma unroll
    for (int r = 0; r < 4; ++r) {
        m_f[r]  = ((float*)(smem + MIZ))[(h * 16 + lhi * 4 + r) * 2];
        iz_f[r] = ((float*)(smem + MIZ))[(h * 16 + lhi * 4 + r) * 2 + 1];
    }

    // per-lane global fragment base pointers
    const unsigned short* kp = kh_g + (size_t)(jg * 16 + l15) * 256 + h * 64 + lhi * 8;
    const unsigned short* vp = vth_g + (size_t)(h * 64 + jg * 32 + l15) * 4096 + lhi * 8;
    const unsigned short* wp = wht_g + (size_t)(h * 64 + jg * 32 + l15) * 4096 + lhi * 8;

    // prefetch tile 0
    s16x8 kf0 = *(const s16x8*)(kp + (size_t)jbase * 256);
    s16x8 kf1 = *(const s16x8*)(kp + (size_t)jbase * 256 + 32);
    s16x8 vf0 = *(const s16x8*)(vp + jbase);
    s16x8 vf1 = *(const s16x8*)(vp + 16 * 4096 + jbase);
    s16x8 wf0 = *(const s16x8*)(wp + jbase);
    s16x8 wf1 = *(const s16x8*)(wp + 16 * 4096 + jbase);
    int   adjc = adj[(size_t)(i0 + srow) * NROWS + jbase + scol];
    float p2c  = p2g[jbase + scol];

    f32x4 pacc[2] = {{0.f,0.f,0.f,0.f},{0.f,0.f,0.f,0.f}};
    f32x4 wacc[2] = {{0.f,0.f,0.f,0.f},{0.f,0.f,0.f,0.f}};
    const float p1v = p1g[i0 + srow];
    // Fixed reference max: >= leaky_relu(p1+p2) + dsum for every j (dsum <= 4).
    float Mfix;
    {
        float s = p1v + p2m[0];
        Mfix = (s > 0.f ? s : ALPHA_LR * s) + 4.0f;
    }
    float Lp = 0.0f;

    const int dwbase = DOTS + h * 1280 + (jg * 16 + l15) * 2;
    const int daddr  = DOTS + h * 1280 + l15 * 80 + lhi * 16;
    const int paddr  = PTIL + l15 * 80 + lhi * 16;

    for (int t = 0; t < ntiles; ++t) {
        const int jn = jbase + ((t + 1 < ntiles) ? (t + 1) * 32 : 0);

        // ---- QK ----
        f32x4 qk = {0.f, 0.f, 0.f, 0.f};
        __builtin_amdgcn_s_setprio(1);
        qk = __builtin_amdgcn_mfma_f32_16x16x32_bf16(qA[0], kf0, qk, 0, 0, 0);
        qk = __builtin_amdgcn_mfma_f32_16x16x32_bf16(qA[1], kf1, qk, 0, 0, 0);
        __builtin_amdgcn_s_setprio(0);
        kf0 = *(const s16x8*)(kp + (size_t)jn * 256);
        kf1 = *(const s16x8*)(kp + (size_t)jn * 256 + 32);
#pragma unroll
        for (int r = 0; r < 4; ++r) {
            float d = __expf(qk[r] * SCALE - m_f[r]) * iz_f[r];
            *(unsigned short*)(smem + dwbase + (lhi * 4 + r) * 80) = bf16_rne(d);
        }
        __syncthreads();  // B1: dots visible

        // ---- PV ----
        {
            s16x8 dA = *(const s16x8*)(smem + daddr);
            __builtin_amdgcn_s_setprio(1);
            pacc[0] = __builtin_amdgcn_mfma_f32_16x16x32_bf16(dA, vf0, pacc[0], 0, 0, 0);
            pacc[1] = __builtin_amdgcn_mfma_f32_16x16x32_bf16(dA, vf1, pacc[1], 0, 0, 0);
            __builtin_amdgcn_s_setprio(0);
        }
        vf0 = *(const s16x8*)(vp + jn);
        vf1 = *(const s16x8*)(vp + 16 * 4096 + jn);

        // ---- outer softmax numerators (fixed reference, no reduction) ----
        {
            float ds = 0.f;
#pragma unroll
            for (int hh = 0; hh < 4; ++hh)
                ds += bf2f(*(const unsigned short*)(smem + DOTS + hh * 1280 + srow * 80 + scol * 2));
            float e = p1v + p2c; e = e > 0.f ? e : ALPHA_LR * e;
            float p = (adjc > 0) ? __expf(e + ds - Mfix) : 0.f;
            Lp += p;
            *(unsigned short*)(smem + PTIL + srow * 80 + scol * 2) = bf16_rne(p);
        }
        adjc = adj[(size_t)(i0 + srow) * NROWS + jn + scol];
        p2c  = p2g[jn + scol];
        __syncthreads();  // B2: ptil visible

        // ---- A@Wh (no rescale) ----
        {
            s16x8 pA = *(const s16x8*)(smem + paddr);
            __builtin_amdgcn_s_setprio(1);
            wacc[0] = __builtin_amdgcn_mfma_f32_16x16x32_bf16(pA, wf0, wacc[0], 0, 0, 0);
            wacc[1] = __builtin_amdgcn_mfma_f32_16x16x32_bf16(pA, wf1, wacc[1], 0, 0, 0);
            __builtin_amdgcn_s_setprio(0);
        }
        wf0 = *(const s16x8*)(wp + jn);
        wf1 = *(const s16x8*)(wp + 16 * 4096 + jn);
    }

    // ---- epilogue: per-chunk partials ----
    Lp = wsum32(Lp);
    if ((ln & 31) == 0)
        ml_o[(size_t)(rt * 3 + ch) * 16 + srow] = Lp;

    const size_t pbase = (size_t)(rt * 3 + ch) * 16 * 256;
#pragma unroll
    for (int nt = 0; nt < 2; ++nt)
#pragma unroll
        for (int r = 0; r < 4; ++r) {
            int row = lhi * 4 + r;
            int col = h * 64 + jg * 32 + nt * 16 + l15;
            pacc_o[pbase + row * 256 + col] = bf16_rne(pacc[nt][r]);
            wacc_o[pbase + row * 256 + col] = bf16_rne(wacc[nt][r]);
        }
}

// ---------------------------------------------------------------------------
// Merge: sum 3 chunks (same fixed max -> plain sums), Wh0 row softmax,
// normalize, elu, store.
// ---------------------------------------------------------------------------
__global__ __launch_bounds__(256) void merge_kernel(
    const unsigned short* __restrict__ pacc_b, const unsigned short* __restrict__ wacc_b,
    const float* __restrict__ ml, float* __restrict__ out)
{
    const int rt = blockIdx.x;
    const int tid = threadIdx.x;
    const int row = tid >> 4;
    const int cg = tid & 15;

    float L = 0.f;
    float p[16], wv[16];
#pragma unroll
    for (int k = 0; k < 16; ++k) { p[k] = 0.f; wv[k] = 0.f; }
#pragma unroll
    for (int c = 0; c < 3; ++c) {
        L += ml[(size_t)(rt * 3 + c) * 16 + row];
        const size_t b = ((size_t)(rt * 3 + c) * 16 + row) * 256 + cg * 16;
        u16x8 pa0 = *(const u16x8*)(pacc_b + b);
        u16x8 pa1 = *(const u16x8*)(pacc_b + b + 8);
        u16x8 wa0 = *(const u16x8*)(wacc_b + b);
        u16x8 wa1 = *(const u16x8*)(wacc_b + b + 8);
#pragma unroll
        for (int k = 0; k < 8; ++k) {
            p[k] += bf2f(pa0[k]);  p[k + 8] += bf2f(pa1[k]);
            wv[k] += bf2f(wa0[k]); wv[k + 8] += bf2f(wa1[k]);
        }
    }
    const float invL = 1.0f / fmaxf(L, 1e-30f);

    float mx = -3.0e38f;
#pragma unroll
    for (int k = 0; k < 16; ++k) mx = fmaxf(mx, p[k]);
    mx = wmax16(mx);
    float sm = 0.f;
#pragma unroll
    for (int k = 0; k < 16; ++k) { p[k] = __expf(p[k] - mx); sm += p[k]; }
    sm = wsum16(sm);
    const float inv = 1.0f / sm;

    float* orow = out + ((size_t)(rt * 16 + row)) * 256 + cg * 16;
#pragma unroll
    for (int k4 = 0; k4 < 4; ++k4) {
        float4 o;
        float v;
        v = wv[k4*4+0] * invL + p[k4*4+0] * inv; o.x = v > 0.f ? v : __expf(v) - 1.f;
        v = wv[k4*4+1] * invL + p[k4*4+1] * inv; o.y = v > 0.f ? v : __expf(v) - 1.f;
        v = wv[k4*4+2] * invL + p[k4*4+2] * inv; o.z = v > 0.f ? v : __expf(v) - 1.f;
        v = wv[k4*4+3] * invL + p[k4*4+3] * inv; o.w = v > 0.f ? v : __expf(v) - 1.f;
        *(float4*)(orow + k4 * 4) = o;
    }
}

extern "C" void kernel_launch(void* const* d_in, const int* in_sizes, int n_in,
                              void* d_out, int out_size, void* d_ws, size_t ws_size,
                              hipStream_t stream)
{
    const float* h      = (const float*)d_in[0];
    const int*   adj    = (const int*)d_in[1];
    const float* W      = (const float*)d_in[2];
    const float* Wl_w   = (const float*)d_in[3];
    const float* Wl_b   = (const float*)d_in[4];
    const float* Wqkv_w = (const float*)d_in[5];
    const float* Wqkv_b = (const float*)d_in[6];
    const float* a      = (const float*)d_in[7];
    float* out = (float*)d_out;

    char* wsb = (char*)d_ws;
    // live during main_attn:
    unsigned short* qh     = (unsigned short*)(wsb + 0);            // 2 MB
    unsigned short* kh     = (unsigned short*)(wsb + 2097152);      // 2 MB
    unsigned short* vth    = (unsigned short*)(wsb + 4194304);      // 2 MB
    unsigned short* wht    = (unsigned short*)(wsb + 6291456);      // 2 MB
    float*          statsb = (float*)(wsb + 8388608);               // 512 KB
    float*          p1b    = (float*)(wsb + 8912896);               // 16 KB
    float*          p2b    = (float*)(wsb + 8929280);               // 16 KB
    float*          p2m    = (float*)(wsb + 8945664);               // 4 KB
    float*          mlb    = (float*)(wsb + 8949760);               // 48 KB
    unsigned short* pacc_b = (unsigned short*)(wsb + 9043968);      // 6 MB
    unsigned short* wacc_b = (unsigned short*)(wsb + 15335424);     // 6 MB -> ends 20.6 MB
    // dead before main_attn, overlaid on pacc_b region:
    float*          Whb    = (float*)(wsb + 9043968);               // 4 MB
    unsigned short* Whi    = (unsigned short*)(wsb + 13238272);     // 256 KB
    unsigned short* Wlo    = Whi + 131072;
    unsigned short* Qhi    = Wlo + 131072;                          // 384 KB
    unsigned short* Qlo    = Qhi + 196608;
    unsigned short* WcThi  = Qlo + 196608;                          // 256 KB
    unsigned short* WcTlo  = WcThi + 131072;

    dim3 blk(256);
    wprep<<<dim3(768), blk, 0, stream>>>(W, Wqkv_w, Whi, Wlo, Qhi, Qlo);
    // WcT[256][512] = Wl_w @ W^T (bf16 hi/lo)
    gemm_mfma<3, false><<<dim3(8, 4), blk, 0, stream>>>(
        Wl_w, Whi, Wlo, nullptr, nullptr, WcThi, WcTlo, nullptr, 256, 512, 256);
    // Wh = h @ WcT^T + Wl_b  (f32 + WhT bf16)
    gemm_mfma<1, true><<<dim3(4, 64), blk, 0, stream>>>(
        h, WcThi, WcTlo, Wl_b, Whb, wht, nullptr, nullptr, 4096, 256, 512);
    // qkv = Wh @ Wqkv_w^T + Wqkv_b  (q,k row bf16; vT bf16)
    gemm_mfma<2, true><<<dim3(12, 64), blk, 0, stream>>>(
        Whb, Qhi, Qlo, Wqkv_b, nullptr, qh, kh, vth, 4096, 768, 256);
    compute_p<<<dim3(256), blk, 0, stream>>>(Whb, a, p1b, p2b);
    p2max_kernel<<<dim3(1), blk, 0, stream>>>(p2b, p2m);
    stats_kernel<<<dim3(1024), blk, 0, stream>>>(qh, kh, statsb);
    main_attn<<<dim3(768), dim3(512), 0, stream>>>(
        qh, kh, vth, wht, statsb, p1b, p2b, p2m, adj, pacc_b, wacc_b, mlb);
    merge_kernel<<<dim3(256), blk, 0, stream>>>(pacc_b, wacc_b, mlb, out);
}

// Round 7
// 286.030 us; speedup vs baseline: 1.2980x; 1.2980x over previous
//
#include <hip/hip_runtime.h>

typedef float  f32x4 __attribute__((ext_vector_type(4)));
typedef short  s16x8 __attribute__((ext_vector_type(8)));
typedef unsigned short u16x8 __attribute__((ext_vector_type(8)));

#define NROWS 4096
#define ALPHA_LR 0.2f
#define SCALE 0.0625f

static __device__ __forceinline__ unsigned short bf16_rne(float x) {
    unsigned u = __float_as_uint(x);
    u += 0x7fffu + ((u >> 16) & 1u);
    return (unsigned short)(u >> 16);
}
static __device__ __forceinline__ unsigned short bf16_trunc(float x) {
    return (unsigned short)(__float_as_uint(x) >> 16);
}
static __device__ __forceinline__ float bf2f(unsigned short h) {
    return __uint_as_float(((unsigned)h) << 16);
}
static __device__ __forceinline__ float bflo(unsigned u) { return __uint_as_float(u << 16); }
static __device__ __forceinline__ float bfhi(unsigned u) { return __uint_as_float(u & 0xffff0000u); }
static __device__ __forceinline__ float wmax16(float v) {
#pragma unroll
    for (int o = 8; o; o >>= 1) v = fmaxf(v, __shfl_xor(v, o, 16));
    return v;
}
static __device__ __forceinline__ float wsum16(float v) {
#pragma unroll
    for (int o = 8; o; o >>= 1) v += __shfl_xor(v, o, 16);
    return v;
}

// ---------------------------------------------------------------------------
// Convert W (512x256) and Wqkv_w (768x256) to bf16 hi/lo.
// ---------------------------------------------------------------------------
__global__ __launch_bounds__(256) void wprep(
    const float* __restrict__ W, const float* __restrict__ Wq,
    unsigned short* __restrict__ Whi, unsigned short* __restrict__ Wlo,
    unsigned short* __restrict__ Qhi, unsigned short* __restrict__ Qlo)
{
    int i = blockIdx.x * 256 + threadIdx.x;
    if (i < 131072) {
        float v = W[i];
        unsigned short hh = bf16_trunc(v);
        Whi[i] = hh; Wlo[i] = bf16_rne(v - bf2f(hh));
    }
    if (i < 196608) {
        float v = Wq[i];
        unsigned short hh = bf16_trunc(v);
        Qhi[i] = hh; Qlo[i] = bf16_rne(v - bf2f(hh));
    }
}

// ---------------------------------------------------------------------------
// MFMA GEMM, 3-term bf16 hi/lo split (unchanged numerics).
// ---------------------------------------------------------------------------
template <int EPI, bool BIAS>
__global__ __launch_bounds__(256) void gemm_mfma(
    const float* __restrict__ A,
    const unsigned short* __restrict__ Bhi, const unsigned short* __restrict__ Blo,
    const float* __restrict__ bias,
    float* __restrict__ C, unsigned short* __restrict__ o0,
    unsigned short* __restrict__ o1, unsigned short* __restrict__ o2,
    int M, int Nn, int K)
{
    __shared__ unsigned short Ah[64][40];
    __shared__ unsigned short Al[64][40];
    __shared__ unsigned short Bh[64][40];
    __shared__ unsigned short Bl[64][40];

    const int tid = threadIdx.x;
    const int w = tid >> 6;
    const int ln = tid & 63;
    const int l15 = ln & 15;
    const int lhi = ln >> 4;
    const int bm = blockIdx.y * 64;
    const int bn = blockIdx.x * 64;
    const int sm = tid >> 2;
    const int sk = (tid & 3) * 8;

    f32x4 acc[4];
#pragma unroll
    for (int cf = 0; cf < 4; ++cf) acc[cf] = (f32x4){0.f, 0.f, 0.f, 0.f};

    const float* arow = &A[(size_t)(bm + sm) * K];
    const unsigned short* bhrow = &Bhi[(size_t)(bn + sm) * K];
    const unsigned short* blrow = &Blo[(size_t)(bn + sm) * K];

    float4 a0r = *(const float4*)(arow + sk);
    float4 a1r = *(const float4*)(arow + sk + 4);
    uint4 bhr = *(const uint4*)(bhrow + sk);
    uint4 blr = *(const uint4*)(blrow + sk);

    for (int k0 = 0; k0 < K; k0 += 32) {
        float vv[8] = {a0r.x, a0r.y, a0r.z, a0r.w, a1r.x, a1r.y, a1r.z, a1r.w};
        unsigned hp[4], lp[4];
#pragma unroll
        for (int q = 0; q < 4; ++q) {
            unsigned short h0 = bf16_trunc(vv[q * 2]);
            unsigned short h1 = bf16_trunc(vv[q * 2 + 1]);
            unsigned short l0 = bf16_rne(vv[q * 2] - bf2f(h0));
            unsigned short l1 = bf16_rne(vv[q * 2 + 1] - bf2f(h1));
            hp[q] = (unsigned)h0 | ((unsigned)h1 << 16);
            lp[q] = (unsigned)l0 | ((unsigned)l1 << 16);
        }
        __syncthreads();
        *(uint4*)&Ah[sm][sk] = make_uint4(hp[0], hp[1], hp[2], hp[3]);
        *(uint4*)&Al[sm][sk] = make_uint4(lp[0], lp[1], lp[2], lp[3]);
        *(uint4*)&Bh[sm][sk] = bhr;
        *(uint4*)&Bl[sm][sk] = blr;
        const int kn = (k0 + 32 < K) ? k0 + 32 : 0;
        a0r = *(const float4*)(arow + kn + sk);
        a1r = *(const float4*)(arow + kn + sk + 4);
        bhr = *(const uint4*)(bhrow + kn + sk);
        blr = *(const uint4*)(blrow + kn + sk);
        __syncthreads();
        s16x8 ah = *(const s16x8*)&Ah[w * 16 + l15][lhi * 8];
        s16x8 al2 = *(const s16x8*)&Al[w * 16 + l15][lhi * 8];
        __builtin_amdgcn_s_setprio(1);
#pragma unroll
        for (int cf = 0; cf < 4; ++cf) {
            s16x8 bh = *(const s16x8*)&Bh[cf * 16 + l15][lhi * 8];
            s16x8 bl = *(const s16x8*)&Bl[cf * 16 + l15][lhi * 8];
            acc[cf] = __builtin_amdgcn_mfma_f32_16x16x32_bf16(ah, bh, acc[cf], 0, 0, 0);
            acc[cf] = __builtin_amdgcn_mfma_f32_16x16x32_bf16(ah, bl, acc[cf], 0, 0, 0);
            acc[cf] = __builtin_amdgcn_mfma_f32_16x16x32_bf16(al2, bh, acc[cf], 0, 0, 0);
        }
        __builtin_amdgcn_s_setprio(0);
    }

#pragma unroll
    for (int cf = 0; cf < 4; ++cf) {
        const int col = bn + cf * 16 + l15;
        float bv = BIAS ? bias[col] : 0.0f;
#pragma unroll
        for (int r = 0; r < 4; ++r) {
            const int row = bm + w * 16 + lhi * 4 + r;
            float v = acc[cf][r] + bv;
            if (EPI == 1) {
                C[(size_t)row * Nn + col] = v;
                o0[(size_t)col * NROWS + row] = bf16_rne(v);
            } else if (EPI == 2) {
                if (col < 256)      o0[(size_t)row * 256 + col] = bf16_rne(v);
                else if (col < 512) o1[(size_t)row * 256 + (col - 256)] = bf16_rne(v);
                else                o2[(size_t)(col - 512) * NROWS + row] = bf16_rne(v);
            } else {
                unsigned short hh = bf16_trunc(v);
                o0[(size_t)row * Nn + col] = hh;
                o1[(size_t)row * Nn + col] = bf16_rne(v - bf2f(hh));
            }
        }
    }
}

// ---------------------------------------------------------------------------
// p1 = Wh @ a[:256], p2 = Wh @ a[256:]
// ---------------------------------------------------------------------------
__global__ __launch_bounds__(256) void compute_p(
    const float* __restrict__ Wh, const float* __restrict__ a,
    float* __restrict__ p1, float* __restrict__ p2)
{
    const int row = blockIdx.x * 16 + (threadIdx.x >> 4);
    const int c = threadIdx.x & 15;
    float s1 = 0.f, s2 = 0.f;
    for (int f = c; f < 256; f += 16) {
        float w = Wh[(size_t)row * 256 + f];
        s1 += w * a[f];
        s2 += w * a[256 + f];
    }
    s1 = wsum16(s1);
    s2 = wsum16(s2);
    if (c == 0) { p1[row] = s1; p2[row] = s2; }
}

// ---------------------------------------------------------------------------
// Global max of p2 (single block).
// ---------------------------------------------------------------------------
__global__ __launch_bounds__(256) void p2max_kernel(
    const float* __restrict__ p2, float* __restrict__ p2m)
{
    __shared__ float red[4];
    const int tid = threadIdx.x;
    float v = -3.0e38f;
#pragma unroll
    for (int k = 0; k < 16; ++k) v = fmaxf(v, p2[tid + k * 256]);
#pragma unroll
    for (int o = 32; o; o >>= 1) v = fmaxf(v, __shfl_xor(v, o, 64));
    if ((tid & 63) == 0) red[tid >> 6] = v;
    __syncthreads();
    if (tid == 0) p2m[0] = fmaxf(fmaxf(red[0], red[1]), fmaxf(red[2], red[3]));
}

// ---------------------------------------------------------------------------
// norms1: per-row squared norms of q (out) and per-block max of k sq-norms.
// ---------------------------------------------------------------------------
__global__ __launch_bounds__(256) void norms1(
    const unsigned short* __restrict__ qh, const unsigned short* __restrict__ kh,
    float* __restrict__ qn2, float* __restrict__ knp)
{
    __shared__ float kn[16][4];
    const int tid = threadIdx.x;
    const int r16 = tid >> 4;
    const int c = tid & 15;
    const int i = blockIdx.x * 16 + r16;
#pragma unroll
    for (int h = 0; h < 4; ++h) {
        float sq = 0.f, sk = 0.f;
#pragma unroll
        for (int d = 0; d < 4; ++d) {
            float qv = bf2f(qh[(size_t)i * 256 + h * 64 + c + d * 16]);
            float kv = bf2f(kh[(size_t)i * 256 + h * 64 + c + d * 16]);
            sq += qv * qv; sk += kv * kv;
        }
        sq = wsum16(sq); sk = wsum16(sk);
        if (c == 0) { qn2[i * 4 + h] = sq; kn[r16][h] = sk; }
    }
    __syncthreads();
    if (tid < 4) {
        float m = 0.f;
#pragma unroll
        for (int r = 0; r < 16; ++r) m = fmaxf(m, kn[r][tid]);
        knp[blockIdx.x * 4 + tid] = m;
    }
}

// ---------------------------------------------------------------------------
// norms2: reduce k-norm partials to Kmax, emit M[i][h] = ||q||*||k||max/16.
// ---------------------------------------------------------------------------
__global__ __launch_bounds__(256) void norms2(
    const float* __restrict__ qn2, const float* __restrict__ knp,
    float* __restrict__ Mb)
{
    __shared__ float red[4][4];
    __shared__ float kmax[4];
    const int tid = threadIdx.x;
    float v[4];
#pragma unroll
    for (int h = 0; h < 4; ++h) v[h] = knp[tid * 4 + h];
#pragma unroll
    for (int h = 0; h < 4; ++h)
#pragma unroll
        for (int o = 32; o; o >>= 1) v[h] = fmaxf(v[h], __shfl_xor(v[h], o, 64));
    if ((tid & 63) == 0) {
#pragma unroll
        for (int h = 0; h < 4; ++h) red[tid >> 6][h] = v[h];
    }
    __syncthreads();
    if (tid < 4)
        kmax[tid] = fmaxf(fmaxf(red[0][tid], red[1][tid]), fmaxf(red[2][tid], red[3][tid]));
    __syncthreads();
    const int i = blockIdx.x * 256 + tid;
#pragma unroll
    for (int h = 0; h < 4; ++h)
        Mb[i * 4 + h] = sqrtf(qn2[i * 4 + h] * kmax[h]) * SCALE;
}

// ---------------------------------------------------------------------------
// zsum: z[i][h][ch] = sum_j exp(s_ij - M_i^h), fixed bound M. No barriers,
// no shuffles in the loop. grid = 256 rowtiles x 4 chunks. 4 waves = 4 heads.
// MFMA sequence MUST match pvds bit-exactly.
// ---------------------------------------------------------------------------
__global__ __launch_bounds__(256) void zsum_kernel(
    const unsigned short* __restrict__ qh_g, const unsigned short* __restrict__ kh_g,
    const float* __restrict__ Mb, float* __restrict__ zpart)
{
    const int tid = threadIdx.x;
    const int h = tid >> 6;
    const int ln = tid & 63;
    const int l15 = ln & 15;
    const int lhi = ln >> 4;
    const int rt = blockIdx.x & 255;
    const int ch = blockIdx.x >> 8;
    const int i0 = rt * 16;

    s16x8 qA[2];
#pragma unroll
    for (int ks = 0; ks < 2; ++ks)
        qA[ks] = *(const s16x8*)(qh_g + (size_t)(i0 + l15) * 256 + h * 64 + ks * 32 + lhi * 8);
    float M[4];
#pragma unroll
    for (int r = 0; r < 4; ++r) M[r] = Mb[(i0 + lhi * 4 + r) * 4 + h];

    float z[4] = {0.f, 0.f, 0.f, 0.f};
    s16x8 kfc[2][2];
#pragma unroll
    for (int nt = 0; nt < 2; ++nt)
#pragma unroll
        for (int ks = 0; ks < 2; ++ks)
            kfc[nt][ks] = *(const s16x8*)(kh_g + (size_t)(ch * 1024 + nt * 16 + l15) * 256 +
                                          h * 64 + ks * 32 + lhi * 8);

    for (int tt = 0; tt < 32; ++tt) {
        const int jn = ch * 1024 + ((tt + 1) & 31) * 32;
        f32x4 acc[2] = {{0.f,0.f,0.f,0.f},{0.f,0.f,0.f,0.f}};
        __builtin_amdgcn_s_setprio(1);
#pragma unroll
        for (int ks = 0; ks < 2; ++ks)
#pragma unroll
            for (int nt = 0; nt < 2; ++nt)
                acc[nt] = __builtin_amdgcn_mfma_f32_16x16x32_bf16(qA[ks], kfc[nt][ks], acc[nt], 0, 0, 0);
        __builtin_amdgcn_s_setprio(0);
#pragma unroll
        for (int nt = 0; nt < 2; ++nt)
#pragma unroll
            for (int ks = 0; ks < 2; ++ks)
                kfc[nt][ks] = *(const s16x8*)(kh_g + (size_t)(jn + nt * 16 + l15) * 256 +
                                              h * 64 + ks * 32 + lhi * 8);
#pragma unroll
        for (int r = 0; r < 4; ++r)
            z[r] += __expf(acc[0][r] * SCALE - M[r]) + __expf(acc[1][r] * SCALE - M[r]);
    }
#pragma unroll
    for (int r = 0; r < 4; ++r) {
        float zz = wsum16(z[r]);
        if (l15 == 0)
            zpart[(((size_t)(i0 + lhi * 4 + r) * 4 + h) * 4) + ch] = zz;
    }
}

// ---------------------------------------------------------------------------
// pvds: dots (normalized, bf16) -> PV partials + dsum (bf16 global).
// grid = 256 rowtiles x 4 chunks, 4 waves = 4 heads, 1 barrier/tile via
// double-buffered dots LDS. QK MFMA sequence identical to zsum.
// ---------------------------------------------------------------------------
__global__ __launch_bounds__(256) void pvds_kernel(
    const unsigned short* __restrict__ qh_g, const unsigned short* __restrict__ kh_g,
    const unsigned short* __restrict__ vth_g,
    const float* __restrict__ Mb, const float* __restrict__ zpart,
    unsigned short* __restrict__ dsum_g, unsigned short* __restrict__ pacc_o)
{
    enum { D0 = 0, D1 = 5120, MIZ = 10240, SMEMSZ = 10752 };
    __shared__ __align__(16) char smem[SMEMSZ];

    const int tid = threadIdx.x;
    const int h = tid >> 6;
    const int ln = tid & 63;
    const int l15 = ln & 15;
    const int lhi = ln >> 4;
    const int rt = blockIdx.x & 255;
    const int ch = blockIdx.x >> 8;
    const int i0 = rt * 16;
    const int srow = tid >> 4;
    const int sc2 = (tid & 15) * 2;

    if (tid < 64) {
        int hh = tid >> 4, row = tid & 15;
        float M = Mb[(i0 + row) * 4 + hh];
        const float* zb = zpart + ((size_t)(i0 + row) * 4 + hh) * 4;
        float z = ((zb[0] + zb[1]) + zb[2]) + zb[3];
        float* fl = (float*)(smem + MIZ);
        fl[(hh * 16 + row) * 2] = M;
        fl[(hh * 16 + row) * 2 + 1] = 1.0f / z;
    }

    s16x8 qA[2];
#pragma unroll
    for (int ks = 0; ks < 2; ++ks)
        qA[ks] = *(const s16x8*)(qh_g + (size_t)(i0 + l15) * 256 + h * 64 + ks * 32 + lhi * 8);
    __syncthreads();

    float m_f[4], iz_f[4];
#pragma unroll
    for (int r = 0; r < 4; ++r) {
        m_f[r]  = ((float*)(smem + MIZ))[(h * 16 + lhi * 4 + r) * 2];
        iz_f[r] = ((float*)(smem + MIZ))[(h * 16 + lhi * 4 + r) * 2 + 1];
    }

    s16x8 kfc[2][2], vfc[2];
#pragma unroll
    for (int nt = 0; nt < 2; ++nt)
#pragma unroll
        for (int ks = 0; ks < 2; ++ks)
            kfc[nt][ks] = *(const s16x8*)(kh_g + (size_t)(ch * 1024 + nt * 16 + l15) * 256 +
                                          h * 64 + ks * 32 + lhi * 8);
#pragma unroll
    for (int nt = 0; nt < 2; ++nt)
        vfc[nt] = *(const s16x8*)(vth_g + (size_t)(h * 64 + nt * 16 + l15) * 4096 +
                                  ch * 1024 + lhi * 8);

    f32x4 pacc[2] = {{0.f,0.f,0.f,0.f},{0.f,0.f,0.f,0.f}};

    for (int tt = 0; tt < 32; ++tt) {
        const int j0 = ch * 1024 + tt * 32;
        const int jn = ch * 1024 + ((tt + 1) & 31) * 32;
        const int buf = (tt & 1) ? D1 : D0;

        // ---- QK (identical sequence to zsum) ----
        f32x4 acc[2] = {{0.f,0.f,0.f,0.f},{0.f,0.f,0.f,0.f}};
        __builtin_amdgcn_s_setprio(1);
#pragma unroll
        for (int ks = 0; ks < 2; ++ks)
#pragma unroll
            for (int nt = 0; nt < 2; ++nt)
                acc[nt] = __builtin_amdgcn_mfma_f32_16x16x32_bf16(qA[ks], kfc[nt][ks], acc[nt], 0, 0, 0);
        __builtin_amdgcn_s_setprio(0);
        // prefetch K(t+1)
#pragma unroll
        for (int nt = 0; nt < 2; ++nt)
#pragma unroll
            for (int ks = 0; ks < 2; ++ks)
                kfc[nt][ks] = *(const s16x8*)(kh_g + (size_t)(jn + nt * 16 + l15) * 256 +
                                              h * 64 + ks * 32 + lhi * 8);
        // dots -> LDS (bf16)
#pragma unroll
        for (int nt = 0; nt < 2; ++nt)
#pragma unroll
            for (int r = 0; r < 4; ++r) {
                float d = __expf(acc[nt][r] * SCALE - m_f[r]) * iz_f[r];
                int row = lhi * 4 + r;
                *(unsigned short*)(smem + buf + h * 1280 + row * 80 + (nt * 16 + l15) * 2) = bf16_rne(d);
            }
        __syncthreads();   // dots(t) visible (single barrier; dbuf covers WAR)

        // ---- PV ----
        {
            s16x8 dA = *(const s16x8*)(smem + buf + h * 1280 + l15 * 80 + lhi * 16);
            __builtin_amdgcn_s_setprio(1);
            pacc[0] = __builtin_amdgcn_mfma_f32_16x16x32_bf16(dA, vfc[0], pacc[0], 0, 0, 0);
            pacc[1] = __builtin_amdgcn_mfma_f32_16x16x32_bf16(dA, vfc[1], pacc[1], 0, 0, 0);
            __builtin_amdgcn_s_setprio(0);
        }
#pragma unroll
        for (int nt = 0; nt < 2; ++nt)
            vfc[nt] = *(const s16x8*)(vth_g + (size_t)(h * 64 + nt * 16 + l15) * 4096 + jn + lhi * 8);

        // ---- dsum (2 cells/thread) -> global bf16 ----
        {
            float ds0 = 0.f, ds1 = 0.f;
#pragma unroll
            for (int hh = 0; hh < 4; ++hh) {
                unsigned u = *(const unsigned*)(smem + buf + hh * 1280 + srow * 80 + sc2 * 2);
                ds0 += bflo(u); ds1 += bfhi(u);
            }
            unsigned pk = (unsigned)bf16_rne(ds0) | ((unsigned)bf16_rne(ds1) << 16);
            *(unsigned*)(dsum_g + (size_t)(i0 + srow) * 4096 + j0 + sc2) = pk;
        }
    }

    const size_t pbase = (size_t)(rt * 4 + ch) * 4096;
#pragma unroll
    for (int nt = 0; nt < 2; ++nt)
#pragma unroll
        for (int r = 0; r < 4; ++r)
            pacc_o[pbase + (lhi * 4 + r) * 256 + h * 64 + nt * 16 + l15] = bf16_rne(pacc[nt][r]);
}

// ---------------------------------------------------------------------------
// outer: masked fixed-ref softmax + A@Wh. grid = 256 rowtiles x 4 chunks,
// 4 waves = 4 feature slices, j-tile 64, 1 barrier/tile (ptil dbuf).
// ---------------------------------------------------------------------------
__global__ __launch_bounds__(256) void outer_kernel(
    const unsigned short* __restrict__ wht_g, const unsigned short* __restrict__ dsum_g,
    const float* __restrict__ p1g, const float* __restrict__ p2g,
    const float* __restrict__ p2m, const int* __restrict__ adj,
    unsigned short* __restrict__ wacc_o, float* __restrict__ Lp_o)
{
    enum { PT0 = 0, PT1 = 2304, SMEMSZ = 4608 };
    __shared__ __align__(16) char smem[SMEMSZ];

    const int tid = threadIdx.x;
    const int w = tid >> 6;
    const int ln = tid & 63;
    const int l15 = ln & 15;
    const int lhi = ln >> 4;
    const int rt = blockIdx.x & 255;
    const int ch = blockIdx.x >> 8;
    const int i0 = rt * 16;
    const int jbase = ch * 1024;
    const int srow = tid >> 4;
    const int sc4 = (tid & 15) * 4;

    const float p1v = p1g[i0 + srow];
    float Mfix;
    {
        float s = p1v + p2m[0];
        Mfix = (s > 0.f ? s : ALPHA_LR * s) + 4.0f;
    }

    // prefetch tile 0
    int4   adjc = *(const int4*)(adj + (size_t)(i0 + srow) * 4096 + jbase + sc4);
    ushort4 dsc = *(const ushort4*)(dsum_g + (size_t)(i0 + srow) * 4096 + jbase + sc4);
    float4 p2c  = *(const float4*)(p2g + jbase + sc4);
    s16x8 wfc[4][2];
#pragma unroll
    for (int nt = 0; nt < 4; ++nt)
#pragma unroll
        for (int ks = 0; ks < 2; ++ks)
            wfc[nt][ks] = *(const s16x8*)(wht_g + (size_t)(w * 64 + nt * 16 + l15) * 4096 +
                                          jbase + ks * 32 + lhi * 8);

    f32x4 acc[4];
#pragma unroll
    for (int nt = 0; nt < 4; ++nt) acc[nt] = (f32x4){0.f, 0.f, 0.f, 0.f};
    float Lacc = 0.0f;

    for (int t = 0; t < 16; ++t) {
        const int jn = jbase + ((t + 1) & 15) * 64;
        const int buf = (t & 1) ? PT1 : PT0;

        // ---- ptil (4 cells) ----
        {
            float pr[4];
            float dsv[4] = {bf2f(dsc.x), bf2f(dsc.y), bf2f(dsc.z), bf2f(dsc.w)};
            float p2v[4] = {p2c.x, p2c.y, p2c.z, p2c.w};
            int   av[4]  = {adjc.x, adjc.y, adjc.z, adjc.w};
#pragma unroll
            for (int k = 0; k < 4; ++k) {
                float e = p1v + p2v[k];
                e = e > 0.f ? e : ALPHA_LR * e;
                pr[k] = (av[k] > 0) ? __expf(e + dsv[k] - Mfix) : 0.f;
                Lacc += pr[k];
            }
            ushort4 pk;
            pk.x = bf16_rne(pr[0]); pk.y = bf16_rne(pr[1]);
            pk.z = bf16_rne(pr[2]); pk.w = bf16_rne(pr[3]);
            *(ushort4*)(smem + buf + srow * 144 + sc4 * 2) = pk;
        }
        // prefetch scalars t+1
        adjc = *(const int4*)(adj + (size_t)(i0 + srow) * 4096 + jn + sc4);
        dsc  = *(const ushort4*)(dsum_g + (size_t)(i0 + srow) * 4096 + jn + sc4);
        p2c  = *(const float4*)(p2g + jn + sc4);
        __syncthreads();   // ptil(t) visible (dbuf covers WAR)

        // ---- A@Wh ----
        {
            s16x8 pa0 = *(const s16x8*)(smem + buf + l15 * 144 + lhi * 16);
            s16x8 pa1 = *(const s16x8*)(smem + buf + l15 * 144 + 64 + lhi * 16);
            __builtin_amdgcn_s_setprio(1);
#pragma unroll
            for (int nt = 0; nt < 4; ++nt) {
                acc[nt] = __builtin_amdgcn_mfma_f32_16x16x32_bf16(pa0, wfc[nt][0], acc[nt], 0, 0, 0);
                acc[nt] = __builtin_amdgcn_mfma_f32_16x16x32_bf16(pa1, wfc[nt][1], acc[nt], 0, 0, 0);
            }
            __builtin_amdgcn_s_setprio(0);
        }
        // prefetch Wh frags t+1
#pragma unroll
        for (int nt = 0; nt < 4; ++nt)
#pragma unroll
            for (int ks = 0; ks < 2; ++ks)
                wfc[nt][ks] = *(const s16x8*)(wht_g + (size_t)(w * 64 + nt * 16 + l15) * 4096 +
                                              jn + ks * 32 + lhi * 8);
    }

    Lacc = wsum16(Lacc);
    if ((tid & 15) == 0) Lp_o[(size_t)(rt * 4 + ch) * 16 + srow] = Lacc;

    const size_t wbase = (size_t)(rt * 4 + ch) * 4096;
#pragma unroll
    for (int nt = 0; nt < 4; ++nt)
#pragma unroll
        for (int r = 0; r < 4; ++r)
            wacc_o[wbase + (lhi * 4 + r) * 256 + w * 64 + nt * 16 + l15] = bf16_rne(acc[nt][r]);
}

// ---------------------------------------------------------------------------
// Merge: sum 4 chunks of pacc/wacc/L, Wh0 row softmax, normalize, elu, store.
// ---------------------------------------------------------------------------
__global__ __launch_bounds__(256) void merge_kernel(
    const unsigned short* __restrict__ pacc_b, const unsigned short* __restrict__ wacc_b,
    const float* __restrict__ Lp, float* __restrict__ out)
{
    const int rt = blockIdx.x;
    const int tid = threadIdx.x;
    const int row = tid >> 4;
    const int cg = tid & 15;

    float L = 0.f;
#pragma unroll
    for (int c = 0; c < 4; ++c) L += Lp[(size_t)(rt * 4 + c) * 16 + row];
    const float invL = 1.0f / fmaxf(L, 1e-30f);

    float p[16], wv[16];
#pragma unroll
    for (int k = 0; k < 16; ++k) { p[k] = 0.f; wv[k] = 0.f; }
#pragma unroll
    for (int c = 0; c < 4; ++c) {
        const size_t b = (size_t)(rt * 4 + c) * 4096 + row * 256 + cg * 16;
        u16x8 pa0 = *(const u16x8*)(pacc_b + b);
        u16x8 pa1 = *(const u16x8*)(pacc_b + b + 8);
        u16x8 wa0 = *(const u16x8*)(wacc_b + b);
        u16x8 wa1 = *(const u16x8*)(wacc_b + b + 8);
#pragma unroll
        for (int k = 0; k < 8; ++k) {
            p[k] += bf2f(pa0[k]);  p[k + 8] += bf2f(pa1[k]);
            wv[k] += bf2f(wa0[k]); wv[k + 8] += bf2f(wa1[k]);
        }
    }

    float mx = -3.0e38f;
#pragma unroll
    for (int k = 0; k < 16; ++k) mx = fmaxf(mx, p[k]);
    mx = wmax16(mx);
    float sm = 0.f;
#pragma unroll
    for (int k = 0; k < 16; ++k) { p[k] = __expf(p[k] - mx); sm += p[k]; }
    sm = wsum16(sm);
    const float inv = 1.0f / sm;

    float* orow = out + ((size_t)(rt * 16 + row)) * 256 + cg * 16;
#pragma unroll
    for (int k4 = 0; k4 < 4; ++k4) {
        float4 o;
        float v;
        v = wv[k4*4+0] * invL + p[k4*4+0] * inv; o.x = v > 0.f ? v : __expf(v) - 1.f;
        v = wv[k4*4+1] * invL + p[k4*4+1] * inv; o.y = v > 0.f ? v : __expf(v) - 1.f;
        v = wv[k4*4+2] * invL + p[k4*4+2] * inv; o.z = v > 0.f ? v : __expf(v) - 1.f;
        v = wv[k4*4+3] * invL + p[k4*4+3] * inv; o.w = v > 0.f ? v : __expf(v) - 1.f;
        *(float4*)(orow + k4 * 4) = o;
    }
}

extern "C" void kernel_launch(void* const* d_in, const int* in_sizes, int n_in,
                              void* d_out, int out_size, void* d_ws, size_t ws_size,
                              hipStream_t stream)
{
    const float* h      = (const float*)d_in[0];
    const int*   adj    = (const int*)d_in[1];
    const float* W      = (const float*)d_in[2];
    const float* Wl_w   = (const float*)d_in[3];
    const float* Wl_b   = (const float*)d_in[4];
    const float* Wqkv_w = (const float*)d_in[5];
    const float* Wqkv_b = (const float*)d_in[6];
    const float* a      = (const float*)d_in[7];
    float* out = (float*)d_out;

    char* wsb = (char*)d_ws;
    unsigned short* qh     = (unsigned short*)(wsb + 0);          // 2 MB
    unsigned short* kh     = (unsigned short*)(wsb + 2097152);    // 2 MB
    unsigned short* vth    = (unsigned short*)(wsb + 4194304);    // 2 MB
    unsigned short* wht    = (unsigned short*)(wsb + 6291456);    // 2 MB
    unsigned short* dsum_b = (unsigned short*)(wsb + 8388608);    // 32 MB
    unsigned short* pacc_b = (unsigned short*)(wsb + 41943040);   // 8 MB
    unsigned short* wacc_b = (unsigned short*)(wsb + 50331648);   // 8 MB
    // Whb overlays wacc region (dead before outer_kernel writes wacc)
    float*          Whb    = (float*)(wsb + 50331648);            // 4 MB
    unsigned short* Whi    = (unsigned short*)(wsb + 58720256);   // 256 KB
    unsigned short* Wlo    = Whi + 131072;
    unsigned short* Qhi    = Wlo + 131072;                        // 384 KB
    unsigned short* Qlo    = Qhi + 196608;
    unsigned short* WcThi  = Qlo + 196608;                        // 256 KB
    unsigned short* WcTlo  = WcThi + 131072;
    float*          p1b    = (float*)(wsb + 60555264);
    float*          p2b    = (float*)(wsb + 60571648);
    float*          p2m    = (float*)(wsb + 60588032);
    float*          qn2    = (float*)(wsb + 60592128);
    float*          knp    = (float*)(wsb + 60657664);
    float*          Mb     = (float*)(wsb + 60661760);
    float*          zpart  = (float*)(wsb + 60727296);
    float*          Lp     = (float*)(wsb + 60989440);

    dim3 blk(256);
    wprep<<<dim3(768), blk, 0, stream>>>(W, Wqkv_w, Whi, Wlo, Qhi, Qlo);
    gemm_mfma<3, false><<<dim3(8, 4), blk, 0, stream>>>(
        Wl_w, Whi, Wlo, nullptr, nullptr, WcThi, WcTlo, nullptr, 256, 512, 256);
    gemm_mfma<1, true><<<dim3(4, 64), blk, 0, stream>>>(
        h, WcThi, WcTlo, Wl_b, Whb, wht, nullptr, nullptr, 4096, 256, 512);
    gemm_mfma<2, true><<<dim3(12, 64), blk, 0, stream>>>(
        Whb, Qhi, Qlo, Wqkv_b, nullptr, qh, kh, vth, 4096, 768, 256);
    compute_p<<<dim3(256), blk, 0, stream>>>(Whb, a, p1b, p2b);
    p2max_kernel<<<dim3(1), blk, 0, stream>>>(p2b, p2m);
    norms1<<<dim3(256), blk, 0, stream>>>(qh, kh, qn2, knp);
    norms2<<<dim3(16), blk, 0, stream>>>(qn2, knp, Mb);
    zsum_kernel<<<dim3(1024), blk, 0, stream>>>(qh, kh, Mb, zpart);
    pvds_kernel<<<dim3(1024), blk, 0, stream>>>(qh, kh, vth, Mb, zpart, dsum_b, pacc_b);
    outer_kernel<<<dim3(1024), blk, 0, stream>>>(wht, dsum_b, p1b, p2b, p2m, adj, wacc_b, Lp);
    merge_kernel<<<dim3(256), blk, 0, stream>>>(pacc_b, wacc_b, Lp, out);
}